// Round 18
// baseline (20.324 us; speedup 1.0000x reference)
//
#include <hip/hip_runtime.h>
#include <hip/hip_bf16.h>
#include <math.h>

#define CIN   64
#define HH    32
#define WW    32
#define OCH   64
#define IKK   576
#define DH    32
#define OIKK  36864
#define WSTR  296    // wslab row stride, bf16 units (592 B, 16B-mult)
#define KHALF 288

typedef __attribute__((ext_vector_type(4))) short short4v;
typedef __attribute__((ext_vector_type(8))) short short8v;
typedef __attribute__((ext_vector_type(4))) float f32x4;

__device__ __forceinline__ float silu_f(float v) {
    return v / (1.0f + __expf(-v));
}
__device__ __forceinline__ unsigned short f2bf(float f) {   // HW RNE cvt
    __hip_bfloat16 h = __float2bfloat16(f);
    return *reinterpret_cast<unsigned short*>(&h);
}
__device__ __forceinline__ float bf2f(unsigned short s) {
    return __uint_as_float(((unsigned int)s) << 16);
}

// 2-deep pipelined K-step: all LDS reads via asm, counted lgkmcnt(3).
#define ISSUE3(Areg, Lreg, Hreg, AOFF, BOFF, BOFF2)                               \
    asm volatile("ds_read_b128 %0, %1 offset:" AOFF : "=v"(Areg) : "v"(wbase));   \
    asm volatile("ds_read_b64_tr_b16 %0, %1 offset:" BOFF : "=v"(Lreg) : "v"(tb));\
    asm volatile("ds_read_b64_tr_b16 %0, %1 offset:" BOFF2 : "=v"(Hreg) : "v"(tb));
#define WAITN3 asm volatile("s_waitcnt lgkmcnt(3)" ::: "memory"); __builtin_amdgcn_sched_barrier(0);
#define WAIT0  asm volatile("s_waitcnt lgkmcnt(0)" ::: "memory"); __builtin_amdgcn_sched_barrier(0);
#define CONSUME(Areg, Lreg, Hreg) {                                               \
    short8v bfr = { Lreg[0],Lreg[1],Lreg[2],Lreg[3],                              \
                    Hreg[0],Hreg[1],Hreg[2],Hreg[3] };                            \
    acc = __builtin_amdgcn_mfma_f32_16x16x32_bf16(Areg, bfr, acc, 0, 0, 0); }

// ONE dispatch, single-writer. block = (b2,q64,oh2) = 256 x 512 threads (8 waves).
// C[64 rows][16 px] = W[64x576] . P[576x16] via mfma_f32_16x16x32_bf16.
__global__ __launch_bounds__(512) void k_one(
    const float* __restrict__ x, const float* __restrict__ c,
    const float* __restrict__ kern, const float* __restrict__ bias,
    const float* __restrict__ w1, const float* __restrict__ b1,
    const float* __restrict__ w2, const float* __restrict__ b2,
    float* __restrict__ out)
{
    __shared__ __align__(16) short patch_t[IKK * 16];   // [k][px] bf16, 18432 B
    __shared__ __align__(16) short wslab[64 * WSTR];    // [row][k-half] bf16, 37888 B
    __shared__ float t_sm[32][17];
    __shared__ float conv_sm[32][17];
    __shared__ float spart[16][17];
    __shared__ float s_sm[16];

    int tid = threadIdx.x;
    int bid = blockIdx.x;
    int oh  = bid & 1;
    int q   = (bid >> 1) & 63;
    int b   = bid >> 7;
    int par = q >> 5, xq = q & 31;

    // ---- wslab staging identity + issue half-0 loads ----
    int srow = tid >> 3;       // 0..63
    int s8   = tid & 7;        // f4 indices s8*9..+9 of each half
    const float* grow = (srow < 32)
        ? (w2   + (size_t)srow * OIKK + q * IKK)
        : (kern + (size_t)((oh << 5) + srow - 32) * IKK);
    const float4* g0 = (const float4*)(grow) + s8 * 9;
    const float4* g1 = (const float4*)(grow + KHALF) + s8 * 9;

    float4 h0[9];
    #pragma unroll
    for (int i = 0; i < 9; ++i) h0[i] = g0[i];

    // ---- stage patch (incremental pp/ikk) ----
    {
        int pp = 0, ikk = tid;   // tid < 512 < 576
        #pragma unroll
        for (int it = 0; it < 18; ++it) {
            int ci = ikk / 9;
            int r  = ikk - ci * 9;
            int kh = r / 3;
            int kw = r - kh * 3;
            int yy = 2 * pp + par + kh - 1;
            int xx = xq + kw - 1;
            float v = 0.0f;
            if (yy >= 0 && yy < HH && xx >= 0 && xx < WW)
                v = x[((b * CIN + ci) * HH + yy) * WW + xx];
            patch_t[ikk * 16 + pp] = (short)f2bf(v);
            ikk += 512;
            if (ikk >= IKK) { ikk -= IKK; ++pp; }
        }
    }

    // ---- store half-0; load+cvt half-1 into bf16 regs (18 VGPR) ----
    #pragma unroll
    for (int i = 0; i < 9; ++i) {
        ushort4 w4 = { f2bf(h0[i].x), f2bf(h0[i].y), f2bf(h0[i].z), f2bf(h0[i].w) };
        *(ushort4*)&wslab[srow * WSTR + (s8 * 9 + i) * 4] = w4;
    }
    ushort4 h1bf[9];
    #pragma unroll
    for (int i = 0; i < 9; ++i) {
        float4 v4 = g1[i];
        h1bf[i] = make_ushort4(f2bf(v4.x), f2bf(v4.y), f2bf(v4.z), f2bf(v4.w));
    }
    __syncthreads();

    int lane = tid & 63;
    int wid  = tid >> 6;
    int rt   = wid & 3;        // row-tile: rows rt*16..+15
    int sub  = wid >> 2;       // K-step split within a half
    int g    = lane >> 4;
    int m    = lane & 15;

    f32x4 acc = {0.f, 0.f, 0.f, 0.f};
    // A addr: wslab row (rt*16+m), step offset = stp*64 B (+g*16 in base)
    unsigned wbase = (unsigned)(size_t)&wslab[(rt * 16 + m) * WSTR] + (unsigned)(g * 16);
    // tr addr: patch_t + (half*288 + g*8 + (m>>2))*32 + (m&3)*8; step delta 1024 B
    unsigned tb0 = (unsigned)(size_t)&patch_t[0]
                 + (unsigned)((g * 8 + (m >> 2)) * 32 + (m & 3) * 8);

    short8v A0, A1;
    short4v L0, H0, L1, H1;

    // ================= compute half 0 =================
    {
        unsigned tb = tb0;
        __builtin_amdgcn_sched_barrier(0);
        if (sub == 0) {   // steps 0..4
            ISSUE3(A0, L0, H0, "0",   "0",    "128")
            ISSUE3(A1, L1, H1, "64",  "1024", "1152")
            WAITN3 CONSUME(A0, L0, H0) ISSUE3(A0, L0, H0, "128", "2048", "2176")
            WAITN3 CONSUME(A1, L1, H1) ISSUE3(A1, L1, H1, "192", "3072", "3200")
            WAITN3 CONSUME(A0, L0, H0) ISSUE3(A0, L0, H0, "256", "4096", "4224")
            WAITN3 CONSUME(A1, L1, H1)
            WAIT0  CONSUME(A0, L0, H0)
        } else {          // steps 5..8
            ISSUE3(A0, L0, H0, "320", "5120", "5248")
            ISSUE3(A1, L1, H1, "384", "6144", "6272")
            WAITN3 CONSUME(A0, L0, H0) ISSUE3(A0, L0, H0, "448", "7168", "7296")
            WAITN3 CONSUME(A1, L1, H1) ISSUE3(A1, L1, H1, "512", "8192", "8320")
            WAITN3 CONSUME(A0, L0, H0)
            WAIT0  CONSUME(A1, L1, H1)
        }
        __builtin_amdgcn_sched_barrier(0);
    }
    __syncthreads();

    // ---- store half-1 from bf16 registers ----
    #pragma unroll
    for (int i = 0; i < 9; ++i)
        *(ushort4*)&wslab[srow * WSTR + (s8 * 9 + i) * 4] = h1bf[i];
    __syncthreads();

    // ================= compute half 1 =================
    {
        unsigned tb = tb0 + (unsigned)(KHALF * 32);
        __builtin_amdgcn_sched_barrier(0);
        if (sub == 0) {
            ISSUE3(A0, L0, H0, "0",   "0",    "128")
            ISSUE3(A1, L1, H1, "64",  "1024", "1152")
            WAITN3 CONSUME(A0, L0, H0) ISSUE3(A0, L0, H0, "128", "2048", "2176")
            WAITN3 CONSUME(A1, L1, H1) ISSUE3(A1, L1, H1, "192", "3072", "3200")
            WAITN3 CONSUME(A0, L0, H0) ISSUE3(A0, L0, H0, "256", "4096", "4224")
            WAITN3 CONSUME(A1, L1, H1)
            WAIT0  CONSUME(A0, L0, H0)
        } else {
            ISSUE3(A0, L0, H0, "320", "5120", "5248")
            ISSUE3(A1, L1, H1, "384", "6144", "6272")
            WAITN3 CONSUME(A0, L0, H0) ISSUE3(A0, L0, H0, "448", "7168", "7296")
            WAITN3 CONSUME(A1, L1, H1) ISSUE3(A1, L1, H1, "512", "8192", "8320")
            WAITN3 CONSUME(A0, L0, H0)
            WAIT0  CONSUME(A1, L1, H1)
        }
        __builtin_amdgcn_sched_barrier(0);
    }
    __syncthreads();   // wslab dead -> alias reduction buffer

    f32x4* red = (f32x4*)wslab;
    if (sub == 1) {
        red[rt * 64 + lane] = acc;
    } else {
        // s partials (tid<256): px = tid>>4, kc = tid&15, 36 k each
        int px = tid >> 4, kc = tid & 15;
        const float* b2q = b2 + q * IKK + kc * 36;
        float a0 = 0.f;
        #pragma unroll
        for (int i = 0; i < 36; ++i)
            a0 = fmaf(bf2f((unsigned short)patch_t[(kc * 36 + i) * 16 + px]), b2q[i], a0);
        spart[px][kc] = a0;
    }
    __syncthreads();

    if (sub == 0) {
        f32x4 o = red[rt * 64 + lane];
        #pragma unroll
        for (int r = 0; r < 4; ++r) {
            int row = rt * 16 + g * 4 + r;     // C/D: row=(lane>>4)*4+reg, col=lane&15
            float v = acc[r] + o[r];
            if (row < 32) t_sm[row][m] = v;
            else          conv_sm[row - 32][m] = v;
        }
    } else if (rt == 0 && lane < 16) {         // tids 256..271: s reduce
        float a0 = 0.f;
        #pragma unroll
        for (int kc = 0; kc < 16; ++kc) a0 += spart[lane][kc];
        s_sm[lane] = a0;
    }
    __syncthreads();

    // ---- H epilogue: inline MLP + dyn + store (1 output/thread) ----
    {
        int o  = tid & 31;
        int p2 = tid >> 5;
        int og = (oh << 5) + o;
        float cb[8];
        #pragma unroll
        for (int i = 0; i < 8; ++i) cb[i] = c[(b << 3) + i];
        int pl = (og << 4) + p2;
        float f0 = (float)(pl >> 5) * (1.0f / 32.0f);
        float f1 = (float)(pl & 31) * (1.0f / 32.0f);
        float dyn = s_sm[p2];
        #pragma unroll 4
        for (int j = 0; j < DH; ++j) {
            float v = b1[j];
            v = fmaf(f0, w1[j], v);
            v = fmaf(f1, w1[DH + j], v);
            #pragma unroll
            for (int i = 0; i < 8; ++i)
                v = fmaf(cb[i], w1[(2 + i) * DH + j], v);
            dyn = fmaf(silu_f(v), t_sm[j][p2], dyn);
        }
        out[((b * OCH + og) << 10) + (p2 << 6) + q] = conv_sm[o][p2] + bias[og] + dyn;
    }
}

extern "C" void kernel_launch(void* const* d_in, const int* in_sizes, int n_in,
                              void* d_out, int out_size, void* d_ws, size_t ws_size,
                              hipStream_t stream) {
    const float* x    = (const float*)d_in[0];
    const float* c    = (const float*)d_in[1];
    const float* kern = (const float*)d_in[2];
    const float* bias = (const float*)d_in[3];
    const float* w1   = (const float*)d_in[4];
    const float* b1   = (const float*)d_in[5];
    const float* w2   = (const float*)d_in[6];
    const float* b2   = (const float*)d_in[7];
    float* out = (float*)d_out;

    k_one<<<256, 512, 0, stream>>>(x, c, kern, bias, w1, b1, w2, b2, out);
}